// Round 1
// baseline (1428.761 us; speedup 1.0000x reference)
//
#include <hip/hip_runtime.h>
#include <math.h>

// ---------------------------------------------------------------------------
// STaRNet forward, fully fused fp32 pipeline.
//
//  k_prep : fold spatial convs+BN+wf-conv+BN into M(50x22)+biasf(50);
//           fold temporal BN into conv taps wtf[450][64] (aligned to a common
//           64-tap window, pad 32) + per-channel bias bt[450].
//  k_main : per (batch, 256-t tile): build xf tile in LDS from x (implicit
//           zero pad), then per-thread t: h[450] on the fly -> y[64] = W^T h
//           in registers; also accumulates sum(h^2) partials (deterministic).
//  k_eig  : per batch: syrk y y^T -> mapped = .95/999*yy^T + .05*mu*I
//           (W^T W = I since W_map is a QR Q); two-sided parallel cyclic
//           Jacobi (8 sweeps); log-eig reconstruction; triu -> FC -> out.
// ---------------------------------------------------------------------------

#define NSWEEP 8

// ws float offsets
#define WS_M      0         // 50*22
#define WS_BIASF  1100      // 50
#define WS_WTF    1152      // 450*64
#define WS_BT     29952     // 450
#define WS_HPART  30402     // 512
#define WS_Y      32768     // 128*64*1001

__global__ void k_prep(
    const float* __restrict__ ws0, const float* __restrict__ ws1, const float* __restrict__ ws2,
    const float* __restrict__ bsg, const float* __restrict__ bsb, const float* __restrict__ bsm, const float* __restrict__ bsv,
    const float* __restrict__ wf,
    const float* __restrict__ bfg, const float* __restrict__ bfb, const float* __restrict__ bfm, const float* __restrict__ bfv,
    const float* __restrict__ wt0, const float* __restrict__ wt1, const float* __restrict__ wt2,
    const float* __restrict__ btg, const float* __restrict__ btb, const float* __restrict__ btm, const float* __restrict__ btv,
    float* __restrict__ wsf)
{
    int tid = threadIdx.x;
    // ---- temporal folded taps (450 channels) ----
    if (tid < 450) {
        int c = tid;
        int i = c / 150, o = c % 150;
        int k = (i == 0) ? 64 : ((i == 1) ? 32 : 16);
        float g = btg[i*150 + o], b = btb[i*150 + o];
        float m = btm[i*150 + o], v = btv[i*150 + o];
        float s = g * rsqrtf(v + 1e-5f);
        wsf[WS_BT + c] = b - s * m;
        float* wrow = wsf + WS_WTF + c * 64;
        for (int t = 0; t < 64; ++t) wrow[t] = 0.f;
        const float* w = (i == 0) ? wt0 : ((i == 1) ? wt1 : wt2);
        int off = 32 - k / 2;
        for (int t = 0; t < k; ++t) wrow[off + t] = s * w[o*k + t];
    }
    // ---- collapsed front-end: M (50x22), biasf (50) ----
    if (tid < 50) {
        int f = tid;
        float sf = bfg[f] * rsqrtf(bfv[f] + 1e-5f);
        float row[22];
        for (int c = 0; c < 22; ++c) row[c] = 0.f;
        float bacc = 0.f;
        for (int j = 0; j < 60; ++j) {
            int i, k, j0; const float* wsp;
            if (j < 22)      { i = 0; k = 1; j0 = j;      wsp = ws0; }
            else if (j < 42) { i = 1; k = 3; j0 = j - 22; wsp = ws1; }
            else             { i = 2; k = 5; j0 = j - 42; wsp = ws2; }
            float si = bsg[i] * rsqrtf(bsv[i] + 1e-5f);
            float bi = bsb[i] - si * bsm[i];
            float wfj = wf[f*60 + j];
            for (int d = 0; d < k; ++d) row[j0 + d] += wfj * si * wsp[d];
            bacc += wfj * bi;
        }
        for (int c = 0; c < 22; ++c) wsf[WS_M + f*22 + c] = sf * row[c];
        wsf[WS_BIASF + f] = sf * (bacc - bfm[f]) + bfb[f];
    }
}

// ---------------------------------------------------------------------------
__global__ __launch_bounds__(256) void k_main(
    const float* __restrict__ x, const float* __restrict__ wsf,
    const float* __restrict__ Wmap, float* __restrict__ y,
    float* __restrict__ hpart)
{
    const int b    = blockIdx.x >> 2;
    const int tile = blockIdx.x & 3;
    const int t0   = tile * 256;
    const int tid  = threadIdx.x;

    __shared__ float xt[50][320];   // xf tile, zero-padded (62.5 KB)
    __shared__ float wred[4];

    const float* Mg    = wsf + WS_M;
    const float* biasf = wsf + WS_BIASF;
    const float* wtf   = wsf + WS_WTF;
    const float* bt    = wsf + WS_BT;

    // ---- phase 0: xf tile straight from x (implicit zero padding) ----
    for (int col = tid; col < 320; col += 256) {
        int tx = t0 + col - 32;
        if (tx >= 0 && tx < 1000) {
            float xv[22];
            #pragma unroll
            for (int c = 0; c < 22; ++c) xv[c] = x[(b*22 + c)*1000 + tx];
            for (int g = 0; g < 50; ++g) {
                float a = biasf[g];
                #pragma unroll
                for (int c = 0; c < 22; ++c) a += Mg[g*22 + c] * xv[c];
                xt[g][col] = a;
            }
        } else {
            for (int g = 0; g < 50; ++g) xt[g][col] = 0.f;
        }
    }
    __syncthreads();

    const int t = t0 + tid;
    const bool act = (t <= 1000);
    float yv[64];
    #pragma unroll
    for (int m = 0; m < 64; ++m) yv[m] = 0.f;
    float hsq = 0.f;

    if (act) {
        for (int g = 0; g < 50; ++g) {
            const float* xb = &xt[g][tid];
            const float* w0 = wtf + (3*g) * 64;         // branch0: 3 rows
            const float* w1 = wtf + (150 + 3*g) * 64;   // branch1
            const float* w2 = wtf + (300 + 3*g) * 64;   // branch2
            float h[9];
            #pragma unroll
            for (int j = 0; j < 9; ++j) h[j] = 0.f;
            #pragma unroll
            for (int tau = 0; tau < 64; ++tau) {
                float xv = xb[tau];
                h[0] += w0[tau]       * xv;
                h[1] += w0[64 + tau]  * xv;
                h[2] += w0[128 + tau] * xv;
                if (tau >= 16 && tau < 48) {
                    h[3] += w1[tau]       * xv;
                    h[4] += w1[64 + tau]  * xv;
                    h[5] += w1[128 + tau] * xv;
                }
                if (tau >= 24 && tau < 40) {
                    h[6] += w2[tau]       * xv;
                    h[7] += w2[64 + tau]  * xv;
                    h[8] += w2[128 + tau] * xv;
                }
            }
            #pragma unroll
            for (int j = 0; j < 9; ++j) {
                int c = (j < 3) ? (3*g + j)
                      : (j < 6) ? (150 + 3*g + (j - 3))
                                : (300 + 3*g + (j - 6));
                float hv = h[j] + bt[c];
                hsq += hv * hv;
                const float* wr = Wmap + c * 64;   // wave-uniform -> s_loads
                #pragma unroll
                for (int m = 0; m < 64; ++m) yv[m] += wr[m] * hv;
            }
        }
        #pragma unroll
        for (int m = 0; m < 64; ++m) y[(b*64 + m)*1001 + t] = yv[m];
    }

    // deterministic block hsq partial
    for (int off = 32; off > 0; off >>= 1) hsq += __shfl_down(hsq, off, 64);
    int wid = tid >> 6, lane = tid & 63;
    if (lane == 0) wred[wid] = hsq;
    __syncthreads();
    if (tid == 0) hpart[blockIdx.x] = wred[0] + wred[1] + wred[2] + wred[3];
}

// ---------------------------------------------------------------------------
__global__ __launch_bounds__(256) void k_eig(
    const float* __restrict__ y, const float* __restrict__ hpart,
    const float* __restrict__ fcw, const float* __restrict__ fcb,
    float* __restrict__ out)
{
    const int b   = blockIdx.x;
    const int tid = threadIdx.x;
    const int mg = tid >> 4, ng = tid & 15;
    const int m0 = mg * 4,  n0 = ng * 4;

    __shared__ float yt[64][129];
    __shared__ float A[64][65];
    __shared__ float V[64][65];
    __shared__ float cc[32], ss[32];
    __shared__ int   pp[32], qq[32];
    __shared__ float le[64];
    __shared__ float red[256];

    // ---- syrk: acc = y y^T (4x4 per thread) ----
    float acc[16];
    #pragma unroll
    for (int i = 0; i < 16; ++i) acc[i] = 0.f;
    for (int tile = 0; tile < 8; ++tile) {
        for (int idx = tid; idx < 64*128; idx += 256) {
            int row = idx >> 7, col = idx & 127;
            int tg = tile * 128 + col;
            yt[row][col] = (tg <= 1000) ? y[(b*64 + row)*1001 + tg] : 0.f;
        }
        __syncthreads();
        for (int tt = 0; tt < 128; ++tt) {
            float ym[4], yn[4];
            #pragma unroll
            for (int i = 0; i < 4; ++i) ym[i] = yt[m0 + i][tt];
            #pragma unroll
            for (int j = 0; j < 4; ++j) yn[j] = yt[n0 + j][tt];
            #pragma unroll
            for (int i = 0; i < 4; ++i)
                #pragma unroll
                for (int j = 0; j < 4; ++j) acc[i*4 + j] += ym[i] * yn[j];
        }
        __syncthreads();
    }
    float hs = hpart[b*4] + hpart[b*4+1] + hpart[b*4+2] + hpart[b*4+3];
    float mu = hs / (999.f * 450.f);
    #pragma unroll
    for (int i = 0; i < 4; ++i)
        #pragma unroll
        for (int j = 0; j < 4; ++j) {
            int mm = m0 + i, nn = n0 + j;
            float vv = acc[i*4 + j] * (0.95f / 999.f) + ((mm == nn) ? 0.05f * mu : 0.f);
            A[mm][nn] = vv;
            V[mm][nn] = (mm == nn) ? 1.f : 0.f;
        }
    __syncthreads();

    // ---- two-sided parallel cyclic Jacobi ----
    for (int sweep = 0; sweep < NSWEEP; ++sweep)
    for (int r = 0; r < 63; ++r) {
        if (tid < 32) {
            int p, q;
            if (tid == 0) { p = 63; q = r; }
            else { p = (r + tid) % 63; q = (r + 63 - tid) % 63; }
            float app = A[p][p], aqq = A[q][q], apq = A[p][q];
            float c = 1.f, s = 0.f;
            if (fabsf(apq) > 1e-20f) {
                float tau = (aqq - app) / (2.f * apq);
                float tt = copysignf(1.f, tau) / (fabsf(tau) + sqrtf(1.f + tau*tau));
                c = 1.f / sqrtf(1.f + tt*tt);
                s = tt * c;
            }
            pp[tid] = p; qq[tid] = q; cc[tid] = c; ss[tid] = s;
        }
        __syncthreads();
        // column update of A and V (A<-A*J, V<-V*J)
        #pragma unroll
        for (int k = 0; k < 8; ++k) {
            int tsk = tid + k*256;
            int j = tsk >> 6, row = tsk & 63;
            int p = pp[j], q = qq[j];
            float c = cc[j], s = ss[j];
            float ap = A[row][p], aq = A[row][q];
            A[row][p] = c*ap - s*aq;
            A[row][q] = s*ap + c*aq;
            float vp = V[row][p], vq = V[row][q];
            V[row][p] = c*vp - s*vq;
            V[row][q] = s*vp + c*vq;
        }
        __syncthreads();
        // row update of A (A<-J^T*A)
        #pragma unroll
        for (int k = 0; k < 8; ++k) {
            int tsk = tid + k*256;
            int j = tsk >> 6, col = tsk & 63;
            int p = pp[j], q = qq[j];
            float c = cc[j], s = ss[j];
            float ap = A[p][col], aq = A[q][col];
            A[p][col] = c*ap - s*aq;
            A[q][col] = s*ap + c*aq;
        }
        __syncthreads();
    }

    // ---- log-eig reconstruction + FC ----
    if (tid < 64) le[tid] = logf(fmaxf(A[tid][tid], 1e-6f));
    __syncthreads();

    float lm[16];
    #pragma unroll
    for (int i = 0; i < 16; ++i) lm[i] = 0.f;
    for (int k = 0; k < 64; ++k) {
        float l = le[k];
        float vm[4], vn[4];
        #pragma unroll
        for (int i = 0; i < 4; ++i) vm[i] = V[m0 + i][k] * l;
        #pragma unroll
        for (int j = 0; j < 4; ++j) vn[j] = V[n0 + j][k];
        #pragma unroll
        for (int i = 0; i < 4; ++i)
            #pragma unroll
            for (int j = 0; j < 4; ++j) lm[i*4 + j] += vm[i] * vn[j];
    }

    float fa[4];
    #pragma unroll
    for (int o = 0; o < 4; ++o) fa[o] = 0.f;
    #pragma unroll
    for (int i = 0; i < 4; ++i)
        #pragma unroll
        for (int j = 0; j < 4; ++j) {
            int gi = m0 + i, gj = n0 + j;
            if (gi <= gj) {
                int p = gi*64 - (gi*(gi-1))/2 + (gj - gi);
                float lv = lm[i*4 + j];
                #pragma unroll
                for (int o = 0; o < 4; ++o) fa[o] += lv * fcw[o*2080 + p];
            }
        }

    for (int o = 0; o < 4; ++o) {
        red[tid] = fa[o];
        __syncthreads();
        for (int off = 128; off > 0; off >>= 1) {
            if (tid < off) red[tid] += red[tid + off];
            __syncthreads();
        }
        if (tid == 0) out[b*4 + o] = red[0] + fcb[o];
        __syncthreads();
    }
}

// ---------------------------------------------------------------------------
extern "C" void kernel_launch(void* const* d_in, const int* in_sizes, int n_in,
                              void* d_out, int out_size, void* d_ws, size_t ws_size,
                              hipStream_t stream) {
    (void)in_sizes; (void)n_in; (void)out_size; (void)ws_size;
    const float* x   = (const float*)d_in[0];
    const float* ws0 = (const float*)d_in[1];
    const float* ws1 = (const float*)d_in[2];
    const float* ws2 = (const float*)d_in[3];
    const float* bsg = (const float*)d_in[4];
    const float* bsb = (const float*)d_in[5];
    const float* bsm = (const float*)d_in[6];
    const float* bsv = (const float*)d_in[7];
    const float* wf  = (const float*)d_in[8];
    const float* bfg = (const float*)d_in[9];
    const float* bfb = (const float*)d_in[10];
    const float* bfm = (const float*)d_in[11];
    const float* bfv = (const float*)d_in[12];
    const float* wt0 = (const float*)d_in[13];
    const float* wt1 = (const float*)d_in[14];
    const float* wt2 = (const float*)d_in[15];
    const float* btg = (const float*)d_in[16];
    const float* btb = (const float*)d_in[17];
    const float* btm = (const float*)d_in[18];
    const float* btv = (const float*)d_in[19];
    const float* Wm  = (const float*)d_in[20];
    const float* fcw = (const float*)d_in[21];
    const float* fcb = (const float*)d_in[22];

    float* wsf   = (float*)d_ws;
    float* yb    = wsf + WS_Y;
    float* hpart = wsf + WS_HPART;

    k_prep<<<1, 512, 0, stream>>>(ws0, ws1, ws2, bsg, bsb, bsm, bsv,
                                  wf, bfg, bfb, bfm, bfv,
                                  wt0, wt1, wt2, btg, btb, btm, btv, wsf);
    k_main<<<512, 256, 0, stream>>>(x, wsf, Wm, yb, hpart);
    k_eig<<<128, 256, 0, stream>>>(yb, hpart, fcw, fcb, (float*)d_out);
}

// Round 2
// 1246.052 us; speedup vs baseline: 1.1466x; 1.1466x over previous
//
#include <hip/hip_runtime.h>
#include <math.h>

// ---------------------------------------------------------------------------
// STaRNet forward, fully fused fp32 pipeline.
//
//  k_prep : fold spatial convs+BN+wf-conv+BN into M(50x22)+biasf(50);
//           fold temporal BN into conv taps wtf[450][64] + bias bt[450].
//  k_main : per (batch, 256-t tile): xf tile in LDS, per-thread t:
//           h[450] on the fly -> y[64] = W^T h (packed fp32);
//           sum(h^2) partials (deterministic).
//  k_eig  : per batch: syrk y y^T -> mapped; in-place 2x2-block parallel
//           cyclic Jacobi (2 barriers/round, early-exit on convergence);
//           log-eig reconstruction; triu -> FC -> out.
// ---------------------------------------------------------------------------

typedef __attribute__((ext_vector_type(2))) float v2f;

// ws float offsets
#define WS_M      0         // 50*22
#define WS_BIASF  1100      // 50
#define WS_WTF    1152      // 450*64
#define WS_BT     29952     // 450
#define WS_HPART  30402     // 512
#define WS_Y      32768     // 128*64*1001

__global__ void k_prep(
    const float* __restrict__ ws0, const float* __restrict__ ws1, const float* __restrict__ ws2,
    const float* __restrict__ bsg, const float* __restrict__ bsb, const float* __restrict__ bsm, const float* __restrict__ bsv,
    const float* __restrict__ wf,
    const float* __restrict__ bfg, const float* __restrict__ bfb, const float* __restrict__ bfm, const float* __restrict__ bfv,
    const float* __restrict__ wt0, const float* __restrict__ wt1, const float* __restrict__ wt2,
    const float* __restrict__ btg, const float* __restrict__ btb, const float* __restrict__ btm, const float* __restrict__ btv,
    float* __restrict__ wsf)
{
    int tid = threadIdx.x;
    if (tid < 450) {
        int c = tid;
        int i = c / 150, o = c % 150;
        int k = (i == 0) ? 64 : ((i == 1) ? 32 : 16);
        float g = btg[i*150 + o], b = btb[i*150 + o];
        float m = btm[i*150 + o], v = btv[i*150 + o];
        float s = g * rsqrtf(v + 1e-5f);
        wsf[WS_BT + c] = b - s * m;
        float* wrow = wsf + WS_WTF + c * 64;
        for (int t = 0; t < 64; ++t) wrow[t] = 0.f;
        const float* w = (i == 0) ? wt0 : ((i == 1) ? wt1 : wt2);
        int off = 32 - k / 2;
        for (int t = 0; t < k; ++t) wrow[off + t] = s * w[o*k + t];
    }
    if (tid < 50) {
        int f = tid;
        float sf = bfg[f] * rsqrtf(bfv[f] + 1e-5f);
        float row[22];
        for (int c = 0; c < 22; ++c) row[c] = 0.f;
        float bacc = 0.f;
        for (int j = 0; j < 60; ++j) {
            int i, k, j0; const float* wsp;
            if (j < 22)      { i = 0; k = 1; j0 = j;      wsp = ws0; }
            else if (j < 42) { i = 1; k = 3; j0 = j - 22; wsp = ws1; }
            else             { i = 2; k = 5; j0 = j - 42; wsp = ws2; }
            float si = bsg[i] * rsqrtf(bsv[i] + 1e-5f);
            float bi = bsb[i] - si * bsm[i];
            float wfj = wf[f*60 + j];
            for (int d = 0; d < k; ++d) row[j0 + d] += wfj * si * wsp[d];
            bacc += wfj * bi;
        }
        for (int c = 0; c < 22; ++c) wsf[WS_M + f*22 + c] = sf * row[c];
        wsf[WS_BIASF + f] = sf * (bacc - bfm[f]) + bfb[f];
    }
}

// ---------------------------------------------------------------------------
__global__ __launch_bounds__(256) void k_main(
    const float* __restrict__ x, const float* __restrict__ wsf,
    const float* __restrict__ Wmap, float* __restrict__ y,
    float* __restrict__ hpart)
{
    const int b    = blockIdx.x >> 2;
    const int tile = blockIdx.x & 3;
    const int t0   = tile * 256;
    const int tid  = threadIdx.x;

    __shared__ float xt[50][320];   // xf tile, zero-padded (62.5 KB)
    __shared__ float wred[4];

    const float* Mg    = wsf + WS_M;
    const float* biasf = wsf + WS_BIASF;
    const float* wtf   = wsf + WS_WTF;
    const float* bt    = wsf + WS_BT;

    for (int col = tid; col < 320; col += 256) {
        int tx = t0 + col - 32;
        if (tx >= 0 && tx < 1000) {
            float xv[22];
            #pragma unroll
            for (int c = 0; c < 22; ++c) xv[c] = x[(b*22 + c)*1000 + tx];
            for (int g = 0; g < 50; ++g) {
                float a = biasf[g];
                #pragma unroll
                for (int c = 0; c < 22; ++c) a += Mg[g*22 + c] * xv[c];
                xt[g][col] = a;
            }
        } else {
            for (int g = 0; g < 50; ++g) xt[g][col] = 0.f;
        }
    }
    __syncthreads();

    const int t = t0 + tid;
    const bool act = (t <= 1000);
    v2f yv2[32];
    #pragma unroll
    for (int m = 0; m < 32; ++m) yv2[m] = (v2f){0.f, 0.f};
    float hsq = 0.f;

    if (act) {
        for (int g = 0; g < 50; ++g) {
            const float* xb = &xt[g][tid];
            const float* w0 = wtf + (3*g) * 64;
            const float* w1 = wtf + (150 + 3*g) * 64;
            const float* w2 = wtf + (300 + 3*g) * 64;
            v2f h2[9];
            #pragma unroll
            for (int j = 0; j < 9; ++j) h2[j] = (v2f){0.f, 0.f};
            #pragma unroll
            for (int tau = 0; tau < 64; tau += 2) {
                v2f xv = (v2f){xb[tau], xb[tau + 1]};
                h2[0] += (*(const v2f*)(w0 + tau))       * xv;
                h2[1] += (*(const v2f*)(w0 + 64 + tau))  * xv;
                h2[2] += (*(const v2f*)(w0 + 128 + tau)) * xv;
                if (tau >= 16 && tau < 48) {
                    h2[3] += (*(const v2f*)(w1 + tau))       * xv;
                    h2[4] += (*(const v2f*)(w1 + 64 + tau))  * xv;
                    h2[5] += (*(const v2f*)(w1 + 128 + tau)) * xv;
                }
                if (tau >= 24 && tau < 40) {
                    h2[6] += (*(const v2f*)(w2 + tau))       * xv;
                    h2[7] += (*(const v2f*)(w2 + 64 + tau))  * xv;
                    h2[8] += (*(const v2f*)(w2 + 128 + tau)) * xv;
                }
            }
            #pragma unroll
            for (int j = 0; j < 9; ++j) {
                int c = (j < 3) ? (3*g + j)
                      : (j < 6) ? (150 + 3*g + (j - 3))
                                : (300 + 3*g + (j - 6));
                float hv = h2[j].x + h2[j].y + bt[c];
                hsq += hv * hv;
                const v2f* wr2 = (const v2f*)(Wmap + c * 64);  // wave-uniform
                v2f hv2 = (v2f){hv, hv};
                #pragma unroll
                for (int m = 0; m < 32; ++m) yv2[m] += wr2[m] * hv2;
            }
        }
        #pragma unroll
        for (int k = 0; k < 32; ++k) {
            y[(b*64 + 2*k)*1001 + t]     = yv2[k].x;
            y[(b*64 + 2*k + 1)*1001 + t] = yv2[k].y;
        }
    }

    for (int off = 32; off > 0; off >>= 1) hsq += __shfl_down(hsq, off, 64);
    int wid = tid >> 6, lane = tid & 63;
    if (lane == 0) wred[wid] = hsq;
    __syncthreads();
    if (tid == 0) hpart[blockIdx.x] = wred[0] + wred[1] + wred[2] + wred[3];
}

// ---------------------------------------------------------------------------
__global__ __launch_bounds__(256) void k_eig(
    const float* __restrict__ y, const float* __restrict__ hpart,
    const float* __restrict__ fcw, const float* __restrict__ fcb,
    float* __restrict__ out)
{
    const int b   = blockIdx.x;
    const int tid = threadIdx.x;
    const int mg = tid >> 4, ng = tid & 15;
    const int m0 = mg * 4,  n0 = ng * 4;

    __shared__ float yt[64][129];
    __shared__ float A[64][65];
    __shared__ float V[64][65];
    __shared__ float2 cs[32];
    __shared__ float conv_flag;
    __shared__ float le[64];
    __shared__ float red[256];

    // ---- syrk: acc = y y^T (4x4 per thread) ----
    float acc[16];
    #pragma unroll
    for (int i = 0; i < 16; ++i) acc[i] = 0.f;
    for (int tile = 0; tile < 8; ++tile) {
        for (int idx = tid; idx < 64*128; idx += 256) {
            int row = idx >> 7, col = idx & 127;
            int tg = tile * 128 + col;
            yt[row][col] = (tg <= 1000) ? y[(b*64 + row)*1001 + tg] : 0.f;
        }
        __syncthreads();
        for (int tt = 0; tt < 128; ++tt) {
            float ym[4], yn[4];
            #pragma unroll
            for (int i = 0; i < 4; ++i) ym[i] = yt[m0 + i][tt];
            #pragma unroll
            for (int j = 0; j < 4; ++j) yn[j] = yt[n0 + j][tt];
            #pragma unroll
            for (int i = 0; i < 4; ++i)
                #pragma unroll
                for (int j = 0; j < 4; ++j) acc[i*4 + j] += ym[i] * yn[j];
        }
        __syncthreads();
    }
    float hs = hpart[b*4] + hpart[b*4+1] + hpart[b*4+2] + hpart[b*4+3];
    float mu = hs / (999.f * 450.f);
    #pragma unroll
    for (int i = 0; i < 4; ++i)
        #pragma unroll
        for (int j = 0; j < 4; ++j) {
            int mm = m0 + i, nn = n0 + j;
            float vv = acc[i*4 + j] * (0.95f / 999.f) + ((mm == nn) ? 0.05f * mu : 0.f);
            A[mm][nn] = vv;
            V[mm][nn] = (mm == nn) ? 1.f : 0.f;
        }
    __syncthreads();

    // ---- in-place 2x2-block parallel cyclic Jacobi, early-exit ----
    const int tI = tid & 31;    // pair index i (A row-pairs; V col-pair)
    const int jg = tid >> 5;    // 0..7

    float swm = 0.f;            // sweep-max off-diag (tid 0 only)
    for (int sweep = 0; sweep < 10; ++sweep) {
        for (int rr = 0; rr < 63; ++rr) {
            if (tid < 32) {
                int p, q;
                if (tid == 0) { p = 63; q = rr; }
                else { p = (rr + tid) % 63; q = (rr + 63 - tid) % 63; }
                float app = A[p][p], aqq = A[q][q], apq = A[p][q];
                float c = 1.f, s = 0.f;
                float aapq = fabsf(apq);
                if (aapq > 1e-30f) {
                    float tau = (aqq - app) / (2.f * apq);
                    float tt = copysignf(1.f, tau) / (fabsf(tau) + sqrtf(1.f + tau*tau));
                    c = rsqrtf(1.f + tt*tt);
                    s = tt * c;
                }
                cs[tid] = make_float2(c, s);
                float mo = aapq;
                float md = fmaxf(fabsf(app), fabsf(aqq));
                #pragma unroll
                for (int m = 1; m < 32; m <<= 1) {
                    mo = fmaxf(mo, __shfl_xor(mo, m, 64));
                    md = fmaxf(md, __shfl_xor(md, m, 64));
                }
                if (tid == 0) {
                    swm = (rr == 0) ? mo : fmaxf(swm, mo);
                    if (rr == 62) conv_flag = (swm <= 4e-7f * md) ? 1.f : 0.f;
                }
            }
            __syncthreads();

            // own row-pair (i = tI)
            int pi, qi;
            if (tI == 0) { pi = 63; qi = rr; }
            else { pi = (rr + tI) % 63; qi = (rr + 63 - tI) % 63; }
            float2 ci = cs[tI];

            // A: 4 blocks (i, j) for j = jg*4 .. jg*4+3   (in-place safe:
            // each 2x2 block is read+written by exactly one thread)
            #pragma unroll
            for (int jj = 0; jj < 4; ++jj) {
                int j = jg*4 + jj;
                int pj, qj;
                if (j == 0) { pj = 63; qj = rr; }
                else { pj = (rr + j) % 63; qj = (rr + 63 - j) % 63; }
                float2 cj = cs[j];
                float B00 = A[pi][pj], B01 = A[pi][qj];
                float B10 = A[qi][pj], B11 = A[qi][qj];
                float t0 = ci.x*B00 - ci.y*B10;
                float t1 = ci.x*B01 - ci.y*B11;
                float t2 = ci.y*B00 + ci.x*B10;
                float t3 = ci.y*B01 + ci.x*B11;
                A[pi][pj] = t0*cj.x - t1*cj.y;
                A[pi][qj] = t0*cj.y + t1*cj.x;
                A[qi][pj] = t2*cj.x - t3*cj.y;
                A[qi][qj] = t2*cj.y + t3*cj.x;
            }
            // V <- V*J : pair tI columns, rows jg*8 .. jg*8+7
            #pragma unroll
            for (int rv = 0; rv < 8; ++rv) {
                int r = jg*8 + rv;
                float vp = V[r][pi], vq = V[r][qi];
                V[r][pi] = ci.x*vp - ci.y*vq;
                V[r][qi] = ci.y*vp + ci.x*vq;
            }
            __syncthreads();
        }
        if (conv_flag != 0.f) break;
    }

    // ---- log-eig reconstruction + FC ----
    if (tid < 64) le[tid] = logf(fmaxf(A[tid][tid], 1e-6f));
    __syncthreads();

    float lm[16];
    #pragma unroll
    for (int i = 0; i < 16; ++i) lm[i] = 0.f;
    for (int k = 0; k < 64; ++k) {
        float l = le[k];
        float vm[4], vn[4];
        #pragma unroll
        for (int i = 0; i < 4; ++i) vm[i] = V[m0 + i][k] * l;
        #pragma unroll
        for (int j = 0; j < 4; ++j) vn[j] = V[n0 + j][k];
        #pragma unroll
        for (int i = 0; i < 4; ++i)
            #pragma unroll
            for (int j = 0; j < 4; ++j) lm[i*4 + j] += vm[i] * vn[j];
    }

    float fa[4];
    #pragma unroll
    for (int o = 0; o < 4; ++o) fa[o] = 0.f;
    #pragma unroll
    for (int i = 0; i < 4; ++i)
        #pragma unroll
        for (int j = 0; j < 4; ++j) {
            int gi = m0 + i, gj = n0 + j;
            if (gi <= gj) {
                int p = gi*64 - (gi*(gi-1))/2 + (gj - gi);
                float lv = lm[i*4 + j];
                #pragma unroll
                for (int o = 0; o < 4; ++o) fa[o] += lv * fcw[o*2080 + p];
            }
        }

    for (int o = 0; o < 4; ++o) {
        red[tid] = fa[o];
        __syncthreads();
        for (int off = 128; off > 0; off >>= 1) {
            if (tid < off) red[tid] += red[tid + off];
            __syncthreads();
        }
        if (tid == 0) out[b*4 + o] = red[0] + fcb[o];
        __syncthreads();
    }
}

// ---------------------------------------------------------------------------
extern "C" void kernel_launch(void* const* d_in, const int* in_sizes, int n_in,
                              void* d_out, int out_size, void* d_ws, size_t ws_size,
                              hipStream_t stream) {
    (void)in_sizes; (void)n_in; (void)out_size; (void)ws_size;
    const float* x   = (const float*)d_in[0];
    const float* ws0 = (const float*)d_in[1];
    const float* ws1 = (const float*)d_in[2];
    const float* ws2 = (const float*)d_in[3];
    const float* bsg = (const float*)d_in[4];
    const float* bsb = (const float*)d_in[5];
    const float* bsm = (const float*)d_in[6];
    const float* bsv = (const float*)d_in[7];
    const float* wf  = (const float*)d_in[8];
    const float* bfg = (const float*)d_in[9];
    const float* bfb = (const float*)d_in[10];
    const float* bfm = (const float*)d_in[11];
    const float* bfv = (const float*)d_in[12];
    const float* wt0 = (const float*)d_in[13];
    const float* wt1 = (const float*)d_in[14];
    const float* wt2 = (const float*)d_in[15];
    const float* btg = (const float*)d_in[16];
    const float* btb = (const float*)d_in[17];
    const float* btm = (const float*)d_in[18];
    const float* btv = (const float*)d_in[19];
    const float* Wm  = (const float*)d_in[20];
    const float* fcw = (const float*)d_in[21];
    const float* fcb = (const float*)d_in[22];

    float* wsf   = (float*)d_ws;
    float* yb    = wsf + WS_Y;
    float* hpart = wsf + WS_HPART;

    k_prep<<<1, 512, 0, stream>>>(ws0, ws1, ws2, bsg, bsb, bsm, bsv,
                                  wf, bfg, bfb, bfm, bfv,
                                  wt0, wt1, wt2, btg, btb, btm, btv, wsf);
    k_main<<<512, 256, 0, stream>>>(x, wsf, Wm, yb, hpart);
    k_eig<<<128, 256, 0, stream>>>(yb, hpart, fcw, fcb, (float*)d_out);
}